// Round 18
// baseline (193.081 us; speedup 1.0000x reference)
//
#include <hip/hip_runtime.h>

#define TPB 256

typedef unsigned int uint32;
typedef unsigned short ushort16;

typedef __attribute__((ext_vector_type(8))) short bf16x8;
typedef __attribute__((ext_vector_type(4))) float f32x4;

// ---------------------------------------------------------------------------
// helpers
// ---------------------------------------------------------------------------
__device__ __forceinline__ unsigned short f2bf(float f) {
  union { float f; unsigned int i; } c; c.f = f;
  unsigned int r = c.i + 0x7fffu + ((c.i >> 16) & 1u);   // RNE
  return (unsigned short)(r >> 16);
}

__device__ __forceinline__ float bflo(uint32 p) {   // low bf16 of packed pair
  union { unsigned int i; float f; } c; c.i = p << 16; return c.f;
}
__device__ __forceinline__ float bfhi(uint32 p) {   // high bf16 of packed pair
  union { unsigned int i; float f; } c; c.i = p & 0xffff0000u; return c.f;
}

__device__ __forceinline__ float bf16val(ushort16 u) {
  union { unsigned int i; float f; } c; c.i = ((uint32)u) << 16; return c.f;
}

// zero deg + pooled-output region (one small dispatch)
__global__ void zero_kernel(int* __restrict__ deg, int N,
                            int* __restrict__ g, int ng) {
  int i = blockIdx.x * blockDim.x + threadIdx.x;
  int stride = gridDim.x * blockDim.x;
  for (int j = i; j < N; j += stride) deg[j] = 0;
  for (int j = i; j < ng; j += stride) g[j] = 0;
}

// ---------------------------------------------------------------------------
// FUSED: count_rank (latency-bound atomics) + bf16 W transposes (independent)
// blocks [0, crBlocks): rank[i] = atomicAdd(&deg[dst[i]], 1)
// blocks [crBlocks, crBlocks+64): wt0/wt1 transpose (16384 elems, 256/block)
// ---------------------------------------------------------------------------
__global__ void crwt_kernel(const int* __restrict__ dst, int E,
                            int* __restrict__ deg, unsigned short* __restrict__ rank,
                            int crBlocks,
                            const float* __restrict__ W0, ushort16* __restrict__ wt0,
                            const float* __restrict__ W1, ushort16* __restrict__ wt1) {
  int t = threadIdx.x;
  if (blockIdx.x < crBlocks) {
    int i = blockIdx.x * TPB + t;
    if (i < E) rank[i] = (unsigned short)atomicAdd(&deg[dst[i]], 1);
  } else {
    int idx = (blockIdx.x - crBlocks) * TPB + t;   // 0..16383
    int k = idx >> 7, c = idx & 127;
    wt0[(size_t)c * 128 + k] = f2bf(W0[idx]);
    wt1[(size_t)c * 128 + k] = f2bf(W1[idx]);
  }
}

// block-wise exclusive scan; also emits per-block total; pass 1 also emits dinv
__global__ void scan_block_kernel(const int* __restrict__ in, int n,
                                  int* __restrict__ out_excl, int* __restrict__ bsum,
                                  float* __restrict__ dinv) {
  __shared__ int sh[TPB];
  int t = threadIdx.x;
  int i = blockIdx.x * TPB + t;
  int v = (i < n) ? in[i] : 0;
  if (dinv != nullptr && i < n) dinv[i] = 1.0f / sqrtf((float)(v + 1));  // +1 self-loop
  sh[t] = v;
  __syncthreads();
  for (int off = 1; off < TPB; off <<= 1) {
    int x = (t >= off) ? sh[t - off] : 0;
    __syncthreads();
    sh[t] += x;
    __syncthreads();
  }
  if (i < n) out_excl[i] = sh[t] - v;          // exclusive
  if (t == TPB - 1 && bsum != nullptr) bsum[blockIdx.x] = sh[t];
}

__global__ void scan_fixup_kernel(int* __restrict__ rs, const int* __restrict__ boff,
                                  int n, int total) {
  int i = blockIdx.x * TPB + threadIdx.x;
  if (i < n) rs[i] += boff[blockIdx.x];
  else if (i == n) rs[n] = total;
}

// ---------------------------------------------------------------------------
// FUSED: CSR fill (atomic-free, ushort col) + layer-0 MFMA GEMM (R17-proven)
// ---------------------------------------------------------------------------
__global__ __launch_bounds__(256) void fill_gemm0_kernel(
    const float* __restrict__ A, const ushort16* __restrict__ wt,
    const float* __restrict__ dinv, ushort16* __restrict__ outz, int nrows,
    int gemmBlocks,
    const int* __restrict__ src, const int* __restrict__ dst,
    const unsigned short* __restrict__ rank, const int* __restrict__ rs,
    int E, unsigned short* __restrict__ col) {
  __shared__ ushort16 Abf[64][128];   // 16 KB (gemm path only)
  int t = threadIdx.x;

  if (blockIdx.x >= gemmBlocks) {
    // ---- fill path ----
    int i = (blockIdx.x - gemmBlocks) * TPB + t;
    if (i < E) {
      int d = dst[i];
      col[rs[d] + (int)rank[i]] = (unsigned short)src[i];
    }
    return;
  }

  // ---- gemm path (proven) ----
  int r0 = blockIdx.x * 64;
  {
    const float4* __restrict__ A4 = (const float4*)A;
#pragma unroll
    for (int i = 0; i < 8; ++i) {
      int idx = t + 256 * i;        // 0..2047
      int r = idx >> 5;             // 0..63
      int cc = idx & 31;            // float4 index within row
      float4 v = make_float4(0.f, 0.f, 0.f, 0.f);
      if (r0 + r < nrows) v = A4[(size_t)(r0 + r) * 32 + cc];
      ushort4 p;
      p.x = f2bf(v.x); p.y = f2bf(v.y); p.z = f2bf(v.z); p.w = f2bf(v.w);
      *(ushort4*)&Abf[r][cc * 4] = p;
    }
  }
  __syncthreads();

  int wave = t >> 6;
  int lane = t & 63;
  int lrow = lane & 15;
  int kg = lane >> 4;               // 0..3
  int rBase = wave * 16;            // 16 rows per wave

  f32x4 acc[8];
#pragma unroll
  for (int ct = 0; ct < 8; ++ct) acc[ct] = (f32x4){0.f, 0.f, 0.f, 0.f};

#pragma unroll
  for (int ks = 0; ks < 4; ++ks) {                 // K = 4 x 32
    bf16x8 af = *(const bf16x8*)&Abf[rBase + lrow][ks * 32 + kg * 8];
#pragma unroll
    for (int ct = 0; ct < 8; ++ct) {               // 8 col-tiles of 16
      bf16x8 bfr = *(const bf16x8*)&wt[(size_t)(ct * 16 + lrow) * 128 + ks * 32 + kg * 8];
      acc[ct] = __builtin_amdgcn_mfma_f32_16x16x32_bf16(af, bfr, acc[ct], 0, 0, 0);
    }
  }

  __syncthreads();   // all waves done reading Abf as input

#pragma unroll
  for (int reg = 0; reg < 4; ++reg) {
    int rl = rBase + kg * 4 + reg;                 // local row (D layout)
    int grow = r0 + rl;
    float di = (grow < nrows) ? dinv[grow] : 0.f;
#pragma unroll
    for (int ct = 0; ct < 8; ++ct) {
      Abf[rl][ct * 16 + lrow] = f2bf(di * acc[ct][reg]);
    }
  }
  __syncthreads();

  {
#pragma unroll
    for (int i = 0; i < 4; ++i) {
      int idx = t + 256 * i;        // 0..1023
      int r = idx >> 4;             // 0..63
      int cc = idx & 15;            // uint4 index within 256B row
      if (r0 + r < nrows)
        ((uint4*)&outz[(size_t)(r0 + r) * 128])[cc] = ((const uint4*)&Abf[r][0])[cc];
    }
  }
}

// ---------------------------------------------------------------------------
// FUSED: layer-1 MFMA GEMM (bf16 A) + pool of z1 half (independent: both read z1h)
// blocks [0, gemmBlocks): gemm. blocks [gemmBlocks, +poolBlocks): pool-z1,
// 64 rows/block, threads t: col t&127, row-half t>>7, segmented sum + atomicAdd.
// ---------------------------------------------------------------------------
__global__ __launch_bounds__(256) void gemm1_poolz1_kernel(
    const ushort16* __restrict__ Ain, const ushort16* __restrict__ wt,
    const float* __restrict__ dinv, ushort16* __restrict__ out, int nrows,
    int gemmBlocks,
    const int* __restrict__ batch, float* __restrict__ g) {
  __shared__ ushort16 Abf[64][128];   // 16 KB (gemm path)
  __shared__ int bsh[64];             // pool path
  int t = threadIdx.x;

  if (blockIdx.x >= gemmBlocks) {
    // ---- pool-z1 path ----
    int r0 = (blockIdx.x - gemmBlocks) * 64;
    int rmax = nrows - r0; if (rmax > 64) rmax = 64;
    if (t < 64 && t < rmax) bsh[t] = batch[r0 + t];
    __syncthreads();
    int c = t & 127;
    int lo = (t >> 7) * 32;
    int hi = lo + 32; if (hi > rmax) hi = rmax;
    if (lo < rmax) {
      float acc = 0.f;
      int cur = bsh[lo];
      for (int i = lo; i < hi; ++i) {
        int b = bsh[i];
        if (b != cur) {
          atomicAdd(&g[(size_t)cur * 256 + c], acc);
          acc = 0.f;
          cur = b;
        }
        acc += bf16val(Ain[(size_t)(r0 + i) * 128 + c]);   // Ain == z1h
      }
      atomicAdd(&g[(size_t)cur * 256 + c], acc);
    }
    return;
  }

  // ---- gemm path (proven) ----
  int r0 = blockIdx.x * 64;
  {
    const uint4* __restrict__ A16 = (const uint4*)Ain;   // 16 uint4 per row
#pragma unroll
    for (int i = 0; i < 4; ++i) {
      int idx = t + 256 * i;        // 0..1023
      int r = idx >> 4;             // 0..63
      int cc = idx & 15;
      uint4 v = make_uint4(0u, 0u, 0u, 0u);
      if (r0 + r < nrows) v = A16[(size_t)(r0 + r) * 16 + cc];
      *(uint4*)&Abf[r][cc * 8] = v;
    }
  }
  __syncthreads();

  int wave = t >> 6;
  int lane = t & 63;
  int lrow = lane & 15;
  int kg = lane >> 4;               // 0..3
  int rBase = wave * 16;            // 16 rows per wave

  f32x4 acc[8];
#pragma unroll
  for (int ct = 0; ct < 8; ++ct) acc[ct] = (f32x4){0.f, 0.f, 0.f, 0.f};

#pragma unroll
  for (int ks = 0; ks < 4; ++ks) {                 // K = 4 x 32
    bf16x8 af = *(const bf16x8*)&Abf[rBase + lrow][ks * 32 + kg * 8];
#pragma unroll
    for (int ct = 0; ct < 8; ++ct) {               // 8 col-tiles of 16
      bf16x8 bfr = *(const bf16x8*)&wt[(size_t)(ct * 16 + lrow) * 128 + ks * 32 + kg * 8];
      acc[ct] = __builtin_amdgcn_mfma_f32_16x16x32_bf16(af, bfr, acc[ct], 0, 0, 0);
    }
  }

  __syncthreads();   // all waves done reading Abf as input

#pragma unroll
  for (int reg = 0; reg < 4; ++reg) {
    int rl = rBase + kg * 4 + reg;                 // local row (D layout)
    int grow = r0 + rl;
    float di = (grow < nrows) ? dinv[grow] : 0.f;
#pragma unroll
    for (int ct = 0; ct < 8; ++ct) {
      Abf[rl][ct * 16 + lrow] = f2bf(di * acc[ct][reg]);
    }
  }
  __syncthreads();

  {
#pragma unroll
    for (int i = 0; i < 4; ++i) {
      int idx = t + 256 * i;        // 0..1023
      int r = idx >> 4;             // 0..63
      int cc = idx & 15;            // uint4 index within 256B row
      if (r0 + r < nrows)
        ((uint4*)&out[(size_t)(r0 + r) * 128])[cc] = ((const uint4*)&Abf[r][0])[cc];
    }
  }
}

// ---------------------------------------------------------------------------
// aggregation (R12-proven 8-wide body, ushort col):
//   z = prelu( dinv[n]*( zws[n] + sum_{e: dst=n} zws[col[e]] ) + b )
//   outh != null -> write bf16 (layer 0); else write f32 to outf (layer 1).
// ---------------------------------------------------------------------------
__global__ __launch_bounds__(256) void aggregate_kernel(
    const ushort16* __restrict__ zws, const int* __restrict__ rs,
    const unsigned short* __restrict__ col,
    const float* __restrict__ dinv, const float* __restrict__ bias,
    const float* __restrict__ alpha,
    float* __restrict__ outf, ushort16* __restrict__ outh, int nrows) {
  int wid = threadIdx.x >> 6;
  int lane = threadIdx.x & 63;
  int node = blockIdx.x * 4 + wid;
  if (node >= nrows) return;
  int c = lane * 2;

  uint32 pv = *(const uint32*)&zws[(size_t)node * 128 + c];
  float accx = bflo(pv), accy = bfhi(pv);

  int e0 = rs[node], e1 = rs[node + 1];
  for (int base = e0; base < e1; base += 64) {
    int nb = e1 - base; if (nb > 64) nb = 64;
    int colv = (base + lane < e1) ? (int)col[base + lane] : 0;  // one coalesced load
    int j = 0;
    for (; j + 8 <= nb; j += 8) {
      int s0 = __shfl(colv, j + 0);
      int s1 = __shfl(colv, j + 1);
      int s2 = __shfl(colv, j + 2);
      int s3 = __shfl(colv, j + 3);
      int s4 = __shfl(colv, j + 4);
      int s5 = __shfl(colv, j + 5);
      int s6 = __shfl(colv, j + 6);
      int s7 = __shfl(colv, j + 7);
      uint32 p0 = *(const uint32*)&zws[(size_t)s0 * 128 + c];
      uint32 p1 = *(const uint32*)&zws[(size_t)s1 * 128 + c];
      uint32 p2 = *(const uint32*)&zws[(size_t)s2 * 128 + c];
      uint32 p3 = *(const uint32*)&zws[(size_t)s3 * 128 + c];
      uint32 p4 = *(const uint32*)&zws[(size_t)s4 * 128 + c];
      uint32 p5 = *(const uint32*)&zws[(size_t)s5 * 128 + c];
      uint32 p6 = *(const uint32*)&zws[(size_t)s6 * 128 + c];
      uint32 p7 = *(const uint32*)&zws[(size_t)s7 * 128 + c];
      accx += bflo(p0) + bflo(p1) + bflo(p2) + bflo(p3)
            + bflo(p4) + bflo(p5) + bflo(p6) + bflo(p7);
      accy += bfhi(p0) + bfhi(p1) + bfhi(p2) + bfhi(p3)
            + bfhi(p4) + bfhi(p5) + bfhi(p6) + bfhi(p7);
    }
    if (j < nb) {   // masked 8-wide tail: clamped index, zero weight for invalid
      int last = nb - 1;
      int i0 = j + 0, i1 = j + 1, i2 = j + 2, i3 = j + 3;
      int i4 = j + 4, i5 = j + 5, i6 = j + 6, i7 = j + 7;
      int s0 = __shfl(colv, i0 < last ? i0 : last);
      int s1 = __shfl(colv, i1 < last ? i1 : last);
      int s2 = __shfl(colv, i2 < last ? i2 : last);
      int s3 = __shfl(colv, i3 < last ? i3 : last);
      int s4 = __shfl(colv, i4 < last ? i4 : last);
      int s5 = __shfl(colv, i5 < last ? i5 : last);
      int s6 = __shfl(colv, i6 < last ? i6 : last);
      int s7 = __shfl(colv, i7 < last ? i7 : last);
      float m0 = (i0 < nb) ? 1.f : 0.f, m1 = (i1 < nb) ? 1.f : 0.f;
      float m2 = (i2 < nb) ? 1.f : 0.f, m3 = (i3 < nb) ? 1.f : 0.f;
      float m4 = (i4 < nb) ? 1.f : 0.f, m5 = (i5 < nb) ? 1.f : 0.f;
      float m6 = (i6 < nb) ? 1.f : 0.f, m7 = (i7 < nb) ? 1.f : 0.f;
      uint32 p0 = *(const uint32*)&zws[(size_t)s0 * 128 + c];
      uint32 p1 = *(const uint32*)&zws[(size_t)s1 * 128 + c];
      uint32 p2 = *(const uint32*)&zws[(size_t)s2 * 128 + c];
      uint32 p3 = *(const uint32*)&zws[(size_t)s3 * 128 + c];
      uint32 p4 = *(const uint32*)&zws[(size_t)s4 * 128 + c];
      uint32 p5 = *(const uint32*)&zws[(size_t)s5 * 128 + c];
      uint32 p6 = *(const uint32*)&zws[(size_t)s6 * 128 + c];
      uint32 p7 = *(const uint32*)&zws[(size_t)s7 * 128 + c];
      accx += m0 * bflo(p0) + m1 * bflo(p1) + m2 * bflo(p2) + m3 * bflo(p3)
            + m4 * bflo(p4) + m5 * bflo(p5) + m6 * bflo(p6) + m7 * bflo(p7);
      accy += m0 * bfhi(p0) + m1 * bfhi(p1) + m2 * bfhi(p2) + m3 * bfhi(p3)
            + m4 * bfhi(p4) + m5 * bfhi(p5) + m6 * bfhi(p6) + m7 * bfhi(p7);
    }
  }

  float di = dinv[node];
  float2 b = *(const float2*)&bias[c];
  float2 al = *(const float2*)&alpha[c];
  float zx = di * accx + b.x, zy = di * accy + b.y;
  zx = zx > 0.f ? zx : al.x * zx;
  zy = zy > 0.f ? zy : al.y * zy;
  if (outh != nullptr) {
    uint32 packed = (uint32)f2bf(zx) | ((uint32)f2bf(zy) << 16);
    *(uint32*)&outh[(size_t)node * 128 + c] = packed;
  } else {
    float2 r; r.x = zx; r.y = zy;
    *(float2*)&outf[(size_t)node * 128 + c] = r;
  }
}

// ---------------------------------------------------------------------------
// pool of z2 half: 64 rows/block, col t&127, row-half t>>7 -> g[:,128:256]
// ---------------------------------------------------------------------------
__global__ __launch_bounds__(256) void pool_z2_kernel(const float* __restrict__ z2,
                                                      const int* __restrict__ batch,
                                                      int n, float* __restrict__ g) {
  __shared__ int bsh[64];
  int t = threadIdx.x;
  int r0 = blockIdx.x * 64;
  int rmax = n - r0; if (rmax > 64) rmax = 64;
  if (t < 64 && t < rmax) bsh[t] = batch[r0 + t];
  __syncthreads();
  int c = t & 127;
  int lo = (t >> 7) * 32;
  int hi = lo + 32; if (hi > rmax) hi = rmax;
  if (lo < rmax) {
    float acc = 0.f;
    int cur = bsh[lo];
    for (int i = lo; i < hi; ++i) {
      int b = bsh[i];
      if (b != cur) {
        atomicAdd(&g[(size_t)cur * 256 + 128 + c], acc);
        acc = 0.f;
        cur = b;
      }
      acc += z2[(size_t)(r0 + i) * 128 + c];
    }
    atomicAdd(&g[(size_t)cur * 256 + 128 + c], acc);
  }
}

// ---------------------------------------------------------------------------
// launcher
// ---------------------------------------------------------------------------
extern "C" void kernel_launch(void* const* d_in, const int* in_sizes, int n_in,
                              void* d_out, int out_size, void* d_ws, size_t ws_size,
                              hipStream_t stream) {
  const float* x     = (const float*)d_in[0];
  const int*   ei    = (const int*)d_in[1];
  const int*   batch = (const int*)d_in[2];
  const float* W0    = (const float*)d_in[3];
  const float* b0    = (const float*)d_in[4];
  const float* a0    = (const float*)d_in[5];
  const float* W1    = (const float*)d_in[6];
  const float* b1    = (const float*)d_in[7];
  const float* a1    = (const float*)d_in[8];
  float* out = (float*)d_out;

  const int N = in_sizes[0] / 128;
  const int E = in_sizes[1] / 2;
  const int G = (out_size - N * 128) / 256;

  const int* src  = ei;       // edge_index[0]
  const int* dstp = ei + E;   // edge_index[1]

  // workspace layout (4-byte words)
  int* w = (int*)d_ws;
  size_t o = 0;
  int*            deg    = w + o; o += (size_t)N;
  int*            rs     = w + o; o += (size_t)((N + 1 + 3) & ~3);
  int*            bsum   = w + o; o += 256;
  int*            boff   = w + o; o += 256;
  unsigned short* col    = (unsigned short*)(w + o); o += (size_t)((E + 1) / 2);
  unsigned short* rank   = (unsigned short*)(w + o); o += (size_t)((E + 1) / 2);
  float*          dinv   = (float*)(w + o); o += (size_t)N;
  ushort16*       wt0    = (ushort16*)(w + o); o += 8192;           // bf16 W0^T
  ushort16*       wt1    = (ushort16*)(w + o); o += 8192;           // bf16 W1^T
  ushort16*       zws    = (ushort16*)(w + o); o += (size_t)N * 64; // bf16 [N,128]
  ushort16*       z1h    = (ushort16*)(w + o); o += (size_t)N * 64; // bf16 [N,128]
  (void)ws_size; (void)n_in;

  const int blkE = (E + TPB - 1) / TPB;
  const int blkN = (N + TPB - 1) / TPB;   // also #scan blocks (<= 256 for N<=65536)
  const int gemmBlocks = (N + 63) / 64;
  const int poolBlocks = (N + 63) / 64;

  float* g = out + (size_t)N * 128;

  // zero deg + g
  zero_kernel<<<512, TPB, 0, stream>>>(deg, N, (int*)g, G * 256);

  // FUSED: count_rank + W transposes
  crwt_kernel<<<blkE + 64, TPB, 0, stream>>>(dstp, E, deg, rank, blkE,
                                             W0, wt0, W1, wt1);

  // exclusive scan of deg -> row_start (rs), hierarchical; pass 1 also emits dinv
  scan_block_kernel<<<blkN, TPB, 0, stream>>>(deg, N, rs, bsum, dinv);
  scan_block_kernel<<<1, TPB, 0, stream>>>(bsum, blkN, boff, nullptr, nullptr);
  scan_fixup_kernel<<<(N + TPB) / TPB, TPB, 0, stream>>>(rs, boff, N, E);

  // FUSED: CSR fill + layer-0 GEMM
  fill_gemm0_kernel<<<gemmBlocks + blkE, TPB, 0, stream>>>(
      x, wt0, dinv, zws, N, gemmBlocks,
      src, dstp, rank, rs, E, col);

  // layer 0 aggregate: z1h = bf16(prelu(dinv*(zws_self + sum) + b0))
  aggregate_kernel<<<(N + 3) / 4, 256, 0, stream>>>(zws, rs, col, dinv, b0, a0,
                                                    nullptr, z1h, N);

  // FUSED: layer-1 GEMM + pool of z1 half
  gemm1_poolz1_kernel<<<gemmBlocks + poolBlocks, 256, 0, stream>>>(
      z1h, wt1, dinv, zws, N, gemmBlocks, batch, g);

  // layer 1 aggregate: z2 = prelu(...) -> d_out (f32)
  aggregate_kernel<<<(N + 3) / 4, 256, 0, stream>>>(zws, rs, col, dinv, b1, a1,
                                                    out, nullptr, N);

  // pool of z2 half -> g[:,128:256]
  pool_z2_kernel<<<poolBlocks, 256, 0, stream>>>(out, batch, N, g);
}

// Round 19
// 187.280 us; speedup vs baseline: 1.0310x; 1.0310x over previous
//
#include <hip/hip_runtime.h>

#define TPB 256
#define PROWS 32

typedef unsigned int uint32;
typedef unsigned short ushort16;

typedef __attribute__((ext_vector_type(8))) short bf16x8;
typedef __attribute__((ext_vector_type(4))) float f32x4;

// ---------------------------------------------------------------------------
// helpers
// ---------------------------------------------------------------------------
__device__ __forceinline__ unsigned short f2bf(float f) {
  union { float f; unsigned int i; } c; c.f = f;
  unsigned int r = c.i + 0x7fffu + ((c.i >> 16) & 1u);   // RNE
  return (unsigned short)(r >> 16);
}

__device__ __forceinline__ float bflo(uint32 p) {   // low bf16 of packed pair
  union { unsigned int i; float f; } c; c.i = p << 16; return c.f;
}
__device__ __forceinline__ float bfhi(uint32 p) {   // high bf16 of packed pair
  union { unsigned int i; float f; } c; c.i = p & 0xffff0000u; return c.f;
}

__device__ __forceinline__ float bf16val(ushort16 u) {
  union { unsigned int i; float f; } c; c.i = ((uint32)u) << 16; return c.f;
}

// fused prep: zero deg + pooled output, bf16-transpose both W (one dispatch)
__global__ void prep_kernel(int* __restrict__ deg, int N,
                            int* __restrict__ g, int ng,
                            const float* __restrict__ W0, ushort16* __restrict__ wt0,
                            const float* __restrict__ W1, ushort16* __restrict__ wt1) {
  int i = blockIdx.x * blockDim.x + threadIdx.x;
  int stride = gridDim.x * blockDim.x;
  for (int j = i; j < N; j += stride) deg[j] = 0;
  for (int j = i; j < ng; j += stride) g[j] = 0;
  for (int j = i; j < 16384; j += stride) {
    int k = j >> 7, c = j & 127;
    wt0[(size_t)c * 128 + k] = f2bf(W0[j]);
    wt1[(size_t)c * 128 + k] = f2bf(W1[j]);
  }
}

// ---------------------------------------------------------------------------
// graph preprocessing: degrees + per-edge rank, CSR-by-dst (ushort col)
// ---------------------------------------------------------------------------
__global__ void count_rank_kernel(const int* __restrict__ dst, int E,
                                  int* __restrict__ deg,
                                  unsigned short* __restrict__ rank) {
  int i = blockIdx.x * blockDim.x + threadIdx.x;
  if (i < E) rank[i] = (unsigned short)atomicAdd(&deg[dst[i]], 1);
}

// block-wise exclusive scan; emits per-block total; also emits dinv
__global__ void scan_block_kernel(const int* __restrict__ in, int n,
                                  int* __restrict__ out_excl, int* __restrict__ bsum,
                                  float* __restrict__ dinv) {
  __shared__ int sh[TPB];
  int t = threadIdx.x;
  int i = blockIdx.x * TPB + t;
  int v = (i < n) ? in[i] : 0;
  if (dinv != nullptr && i < n) dinv[i] = 1.0f / sqrtf((float)(v + 1));  // +1 self-loop
  sh[t] = v;
  __syncthreads();
  for (int off = 1; off < TPB; off <<= 1) {
    int x = (t >= off) ? sh[t - off] : 0;
    __syncthreads();
    sh[t] += x;
    __syncthreads();
  }
  if (i < n) out_excl[i] = sh[t] - v;          // exclusive
  if (t == TPB - 1 && bsum != nullptr) bsum[blockIdx.x] = sh[t];
}

// fixup with inline scan of the block sums (nb <= TPB): removes the middle
// 1-block scan dispatch. Each block scans bsum[0..nb) in LDS and uses the
// exclusive prefix at its own index.
__global__ void scan_fixup2_kernel(int* __restrict__ rs, const int* __restrict__ bsum,
                                   int nb, int n, int total) {
  __shared__ int sh[TPB];
  int t = threadIdx.x;
  int v = (t < nb) ? bsum[t] : 0;
  sh[t] = v;
  __syncthreads();
  for (int off = 1; off < TPB; off <<= 1) {
    int x = (t >= off) ? sh[t - off] : 0;
    __syncthreads();
    sh[t] += x;
    __syncthreads();
  }
  int b = blockIdx.x;
  int boff = (b < nb) ? (sh[b] - bsum[b]) : ((nb > 0) ? sh[nb - 1] : 0);  // exclusive
  int i = b * TPB + t;
  if (i < n) rs[i] += boff;
  else if (i == n) rs[n] = total;
}

// ---------------------------------------------------------------------------
// FUSED: CSR fill (atomic-free, ushort col) + layer-0 MFMA GEMM (R17-proven)
// ---------------------------------------------------------------------------
__global__ __launch_bounds__(256) void fill_gemm0_kernel(
    const float* __restrict__ A, const ushort16* __restrict__ wt,
    const float* __restrict__ dinv, ushort16* __restrict__ outz, int nrows,
    int gemmBlocks,
    const int* __restrict__ src, const int* __restrict__ dst,
    const unsigned short* __restrict__ rank, const int* __restrict__ rs,
    int E, unsigned short* __restrict__ col) {
  __shared__ ushort16 Abf[64][128];   // 16 KB (gemm path only)
  int t = threadIdx.x;

  if (blockIdx.x >= gemmBlocks) {
    // ---- fill path ----
    int i = (blockIdx.x - gemmBlocks) * TPB + t;
    if (i < E) {
      int d = dst[i];
      col[rs[d] + (int)rank[i]] = (unsigned short)src[i];
    }
    return;
  }

  // ---- gemm path (proven) ----
  int r0 = blockIdx.x * 64;
  {
    const float4* __restrict__ A4 = (const float4*)A;
#pragma unroll
    for (int i = 0; i < 8; ++i) {
      int idx = t + 256 * i;        // 0..2047
      int r = idx >> 5;             // 0..63
      int cc = idx & 31;            // float4 index within row
      float4 v = make_float4(0.f, 0.f, 0.f, 0.f);
      if (r0 + r < nrows) v = A4[(size_t)(r0 + r) * 32 + cc];
      ushort4 p;
      p.x = f2bf(v.x); p.y = f2bf(v.y); p.z = f2bf(v.z); p.w = f2bf(v.w);
      *(ushort4*)&Abf[r][cc * 4] = p;
    }
  }
  __syncthreads();

  int wave = t >> 6;
  int lane = t & 63;
  int lrow = lane & 15;
  int kg = lane >> 4;               // 0..3
  int rBase = wave * 16;            // 16 rows per wave

  f32x4 acc[8];
#pragma unroll
  for (int ct = 0; ct < 8; ++ct) acc[ct] = (f32x4){0.f, 0.f, 0.f, 0.f};

#pragma unroll
  for (int ks = 0; ks < 4; ++ks) {                 // K = 4 x 32
    bf16x8 af = *(const bf16x8*)&Abf[rBase + lrow][ks * 32 + kg * 8];
#pragma unroll
    for (int ct = 0; ct < 8; ++ct) {               // 8 col-tiles of 16
      bf16x8 bfr = *(const bf16x8*)&wt[(size_t)(ct * 16 + lrow) * 128 + ks * 32 + kg * 8];
      acc[ct] = __builtin_amdgcn_mfma_f32_16x16x32_bf16(af, bfr, acc[ct], 0, 0, 0);
    }
  }

  __syncthreads();   // all waves done reading Abf as input

#pragma unroll
  for (int reg = 0; reg < 4; ++reg) {
    int rl = rBase + kg * 4 + reg;                 // local row (D layout)
    int grow = r0 + rl;
    float di = (grow < nrows) ? dinv[grow] : 0.f;
#pragma unroll
    for (int ct = 0; ct < 8; ++ct) {
      Abf[rl][ct * 16 + lrow] = f2bf(di * acc[ct][reg]);
    }
  }
  __syncthreads();

  {
#pragma unroll
    for (int i = 0; i < 4; ++i) {
      int idx = t + 256 * i;        // 0..1023
      int r = idx >> 4;             // 0..63
      int cc = idx & 15;            // uint4 index within 256B row
      if (r0 + r < nrows)
        ((uint4*)&outz[(size_t)(r0 + r) * 128])[cc] = ((const uint4*)&Abf[r][0])[cc];
    }
  }
}

// ---------------------------------------------------------------------------
// MFMA GEMM (layer 1, bf16 A input): zws[N,128](bf16) = dinv[r] * (A @ W)
// ---------------------------------------------------------------------------
__global__ __launch_bounds__(256) void gemm_mfma_bf16_kernel(
    const ushort16* __restrict__ Ain, const ushort16* __restrict__ wt,
    const float* __restrict__ dinv, ushort16* __restrict__ out, int nrows) {
  __shared__ ushort16 Abf[64][128];   // 16 KB bf16 A-tile; reused as out staging
  int t = threadIdx.x;
  int r0 = blockIdx.x * 64;

  {
    const uint4* __restrict__ A16 = (const uint4*)Ain;   // 16 uint4 per row
#pragma unroll
    for (int i = 0; i < 4; ++i) {
      int idx = t + 256 * i;        // 0..1023
      int r = idx >> 4;             // 0..63
      int cc = idx & 15;
      uint4 v = make_uint4(0u, 0u, 0u, 0u);
      if (r0 + r < nrows) v = A16[(size_t)(r0 + r) * 16 + cc];
      *(uint4*)&Abf[r][cc * 8] = v;
    }
  }
  __syncthreads();

  int wave = t >> 6;
  int lane = t & 63;
  int lrow = lane & 15;
  int kg = lane >> 4;               // 0..3
  int rBase = wave * 16;            // 16 rows per wave

  f32x4 acc[8];
#pragma unroll
  for (int ct = 0; ct < 8; ++ct) acc[ct] = (f32x4){0.f, 0.f, 0.f, 0.f};

#pragma unroll
  for (int ks = 0; ks < 4; ++ks) {                 // K = 4 x 32
    bf16x8 af = *(const bf16x8*)&Abf[rBase + lrow][ks * 32 + kg * 8];
#pragma unroll
    for (int ct = 0; ct < 8; ++ct) {               // 8 col-tiles of 16
      bf16x8 bfr = *(const bf16x8*)&wt[(size_t)(ct * 16 + lrow) * 128 + ks * 32 + kg * 8];
      acc[ct] = __builtin_amdgcn_mfma_f32_16x16x32_bf16(af, bfr, acc[ct], 0, 0, 0);
    }
  }

  __syncthreads();   // all waves done reading Abf as input

#pragma unroll
  for (int reg = 0; reg < 4; ++reg) {
    int rl = rBase + kg * 4 + reg;                 // local row (D layout)
    int grow = r0 + rl;
    float di = (grow < nrows) ? dinv[grow] : 0.f;
#pragma unroll
    for (int ct = 0; ct < 8; ++ct) {
      Abf[rl][ct * 16 + lrow] = f2bf(di * acc[ct][reg]);
    }
  }
  __syncthreads();

  {
#pragma unroll
    for (int i = 0; i < 4; ++i) {
      int idx = t + 256 * i;        // 0..1023
      int r = idx >> 4;             // 0..63
      int cc = idx & 15;            // uint4 index within 256B row
      if (r0 + r < nrows)
        ((uint4*)&out[(size_t)(r0 + r) * 128])[cc] = ((const uint4*)&Abf[r][0])[cc];
    }
  }
}

// ---------------------------------------------------------------------------
// aggregation (R12-proven 8-wide body, ushort col):
//   z = prelu( dinv[n]*( zws[n] + sum_{e: dst=n} zws[col[e]] ) + b )
//   outh != null -> write bf16 (layer 0); else write f32 to outf (layer 1).
// ---------------------------------------------------------------------------
__global__ __launch_bounds__(256) void aggregate_kernel(
    const ushort16* __restrict__ zws, const int* __restrict__ rs,
    const unsigned short* __restrict__ col,
    const float* __restrict__ dinv, const float* __restrict__ bias,
    const float* __restrict__ alpha,
    float* __restrict__ outf, ushort16* __restrict__ outh, int nrows) {
  int wid = threadIdx.x >> 6;
  int lane = threadIdx.x & 63;
  int node = blockIdx.x * 4 + wid;
  if (node >= nrows) return;
  int c = lane * 2;

  uint32 pv = *(const uint32*)&zws[(size_t)node * 128 + c];
  float accx = bflo(pv), accy = bfhi(pv);

  int e0 = rs[node], e1 = rs[node + 1];
  for (int base = e0; base < e1; base += 64) {
    int nb = e1 - base; if (nb > 64) nb = 64;
    int colv = (base + lane < e1) ? (int)col[base + lane] : 0;  // one coalesced load
    int j = 0;
    for (; j + 8 <= nb; j += 8) {
      int s0 = __shfl(colv, j + 0);
      int s1 = __shfl(colv, j + 1);
      int s2 = __shfl(colv, j + 2);
      int s3 = __shfl(colv, j + 3);
      int s4 = __shfl(colv, j + 4);
      int s5 = __shfl(colv, j + 5);
      int s6 = __shfl(colv, j + 6);
      int s7 = __shfl(colv, j + 7);
      uint32 p0 = *(const uint32*)&zws[(size_t)s0 * 128 + c];
      uint32 p1 = *(const uint32*)&zws[(size_t)s1 * 128 + c];
      uint32 p2 = *(const uint32*)&zws[(size_t)s2 * 128 + c];
      uint32 p3 = *(const uint32*)&zws[(size_t)s3 * 128 + c];
      uint32 p4 = *(const uint32*)&zws[(size_t)s4 * 128 + c];
      uint32 p5 = *(const uint32*)&zws[(size_t)s5 * 128 + c];
      uint32 p6 = *(const uint32*)&zws[(size_t)s6 * 128 + c];
      uint32 p7 = *(const uint32*)&zws[(size_t)s7 * 128 + c];
      accx += bflo(p0) + bflo(p1) + bflo(p2) + bflo(p3)
            + bflo(p4) + bflo(p5) + bflo(p6) + bflo(p7);
      accy += bfhi(p0) + bfhi(p1) + bfhi(p2) + bfhi(p3)
            + bfhi(p4) + bfhi(p5) + bfhi(p6) + bfhi(p7);
    }
    if (j < nb) {   // masked 8-wide tail: clamped index, zero weight for invalid
      int last = nb - 1;
      int i0 = j + 0, i1 = j + 1, i2 = j + 2, i3 = j + 3;
      int i4 = j + 4, i5 = j + 5, i6 = j + 6, i7 = j + 7;
      int s0 = __shfl(colv, i0 < last ? i0 : last);
      int s1 = __shfl(colv, i1 < last ? i1 : last);
      int s2 = __shfl(colv, i2 < last ? i2 : last);
      int s3 = __shfl(colv, i3 < last ? i3 : last);
      int s4 = __shfl(colv, i4 < last ? i4 : last);
      int s5 = __shfl(colv, i5 < last ? i5 : last);
      int s6 = __shfl(colv, i6 < last ? i6 : last);
      int s7 = __shfl(colv, i7 < last ? i7 : last);
      float m0 = (i0 < nb) ? 1.f : 0.f, m1 = (i1 < nb) ? 1.f : 0.f;
      float m2 = (i2 < nb) ? 1.f : 0.f, m3 = (i3 < nb) ? 1.f : 0.f;
      float m4 = (i4 < nb) ? 1.f : 0.f, m5 = (i5 < nb) ? 1.f : 0.f;
      float m6 = (i6 < nb) ? 1.f : 0.f, m7 = (i7 < nb) ? 1.f : 0.f;
      uint32 p0 = *(const uint32*)&zws[(size_t)s0 * 128 + c];
      uint32 p1 = *(const uint32*)&zws[(size_t)s1 * 128 + c];
      uint32 p2 = *(const uint32*)&zws[(size_t)s2 * 128 + c];
      uint32 p3 = *(const uint32*)&zws[(size_t)s3 * 128 + c];
      uint32 p4 = *(const uint32*)&zws[(size_t)s4 * 128 + c];
      uint32 p5 = *(const uint32*)&zws[(size_t)s5 * 128 + c];
      uint32 p6 = *(const uint32*)&zws[(size_t)s6 * 128 + c];
      uint32 p7 = *(const uint32*)&zws[(size_t)s7 * 128 + c];
      accx += m0 * bflo(p0) + m1 * bflo(p1) + m2 * bflo(p2) + m3 * bflo(p3)
            + m4 * bflo(p4) + m5 * bflo(p5) + m6 * bflo(p6) + m7 * bflo(p7);
      accy += m0 * bfhi(p0) + m1 * bfhi(p1) + m2 * bfhi(p2) + m3 * bfhi(p3)
            + m4 * bfhi(p4) + m5 * bfhi(p5) + m6 * bfhi(p6) + m7 * bfhi(p7);
    }
  }

  float di = dinv[node];
  float2 b = *(const float2*)&bias[c];
  float2 al = *(const float2*)&alpha[c];
  float zx = di * accx + b.x, zy = di * accy + b.y;
  zx = zx > 0.f ? zx : al.x * zx;
  zy = zy > 0.f ? zy : al.y * zy;
  if (outh != nullptr) {
    uint32 packed = (uint32)f2bf(zx) | ((uint32)f2bf(zy) << 16);
    *(uint32*)&outh[(size_t)node * 128 + c] = packed;
  } else {
    float2 r; r.x = zx; r.y = zy;
    *(float2*)&outf[(size_t)node * 128 + c] = r;
  }
}

// ---------------------------------------------------------------------------
// pooling (R14-proven): g[gi] = [ sum z1(bf16) | sum z2(f32) ]  (batch sorted)
// ---------------------------------------------------------------------------
__global__ __launch_bounds__(256) void pool_kernel(const ushort16* __restrict__ z1h,
                                                   const float* __restrict__ z2,
                                                   const int* __restrict__ batch, int n,
                                                   float* __restrict__ g) {
  int r0 = blockIdx.x * PROWS;
  int t = threadIdx.x;
  __shared__ int bsh[PROWS];
  int rmax = n - r0; if (rmax > PROWS) rmax = PROWS;
  if (t < PROWS && t < rmax) bsh[t] = batch[r0 + t];
  __syncthreads();

  int c = t & 127;
  float acc = 0.f;
  int cur = bsh[0];
  if (t < 128) {
    for (int i = 0; i < rmax; ++i) {
      int b = bsh[i];
      if (b != cur) {
        atomicAdd(&g[(size_t)cur * 256 + t], acc);
        acc = 0.f;
        cur = b;
      }
      acc += bf16val(z1h[(size_t)(r0 + i) * 128 + c]);
    }
  } else {
    for (int i = 0; i < rmax; ++i) {
      int b = bsh[i];
      if (b != cur) {
        atomicAdd(&g[(size_t)cur * 256 + t], acc);
        acc = 0.f;
        cur = b;
      }
      acc += z2[(size_t)(r0 + i) * 128 + c];
    }
  }
  atomicAdd(&g[(size_t)cur * 256 + t], acc);
}

// ---------------------------------------------------------------------------
// launcher
// ---------------------------------------------------------------------------
extern "C" void kernel_launch(void* const* d_in, const int* in_sizes, int n_in,
                              void* d_out, int out_size, void* d_ws, size_t ws_size,
                              hipStream_t stream) {
  const float* x     = (const float*)d_in[0];
  const int*   ei    = (const int*)d_in[1];
  const int*   batch = (const int*)d_in[2];
  const float* W0    = (const float*)d_in[3];
  const float* b0    = (const float*)d_in[4];
  const float* a0    = (const float*)d_in[5];
  const float* W1    = (const float*)d_in[6];
  const float* b1    = (const float*)d_in[7];
  const float* a1    = (const float*)d_in[8];
  float* out = (float*)d_out;

  const int N = in_sizes[0] / 128;
  const int E = in_sizes[1] / 2;
  const int G = (out_size - N * 128) / 256;

  const int* src  = ei;       // edge_index[0]
  const int* dstp = ei + E;   // edge_index[1]

  // workspace layout (4-byte words)
  int* w = (int*)d_ws;
  size_t o = 0;
  int*            deg    = w + o; o += (size_t)N;
  int*            rs     = w + o; o += (size_t)((N + 1 + 3) & ~3);
  int*            bsum   = w + o; o += 256;
  int*            boff   = w + o; o += 256;
  unsigned short* col    = (unsigned short*)(w + o); o += (size_t)((E + 1) / 2);
  unsigned short* rank   = (unsigned short*)(w + o); o += (size_t)((E + 1) / 2);
  float*          dinv   = (float*)(w + o); o += (size_t)N;
  ushort16*       wt0    = (ushort16*)(w + o); o += 8192;           // bf16 W0^T
  ushort16*       wt1    = (ushort16*)(w + o); o += 8192;           // bf16 W1^T
  ushort16*       zws    = (ushort16*)(w + o); o += (size_t)N * 64; // bf16 [N,128]
  ushort16*       z1h    = (ushort16*)(w + o); o += (size_t)N * 64; // bf16 [N,128]
  (void)ws_size; (void)n_in; (void)boff;

  const int blkE = (E + TPB - 1) / TPB;
  const int blkN = (N + TPB - 1) / TPB;   // #scan blocks (<= 256 for N<=65536)
  const int gemmBlocks = (N + 63) / 64;

  float* g = out + (size_t)N * 128;

  // fused prep: zero deg + g, transpose both W to bf16
  prep_kernel<<<512, TPB, 0, stream>>>(deg, N, (int*)g, G * 256, W0, wt0, W1, wt1);

  // degrees + per-edge rank
  count_rank_kernel<<<blkE, TPB, 0, stream>>>(dstp, E, deg, rank);

  // exclusive scan of deg -> rs (2 dispatches: block scan + inline-scan fixup)
  scan_block_kernel<<<blkN, TPB, 0, stream>>>(deg, N, rs, bsum, dinv);
  scan_fixup2_kernel<<<(N + TPB) / TPB, TPB, 0, stream>>>(rs, bsum, blkN, N, E);

  // FUSED: CSR fill + layer-0 GEMM
  fill_gemm0_kernel<<<gemmBlocks + blkE, TPB, 0, stream>>>(
      x, wt0, dinv, zws, N, gemmBlocks,
      src, dstp, rank, rs, E, col);

  // layer 0 aggregate: z1h = bf16(prelu(dinv*(zws_self + sum) + b0))
  aggregate_kernel<<<(N + 3) / 4, 256, 0, stream>>>(zws, rs, col, dinv, b0, a0,
                                                    nullptr, z1h, N);

  // layer 1: zws = bf16(dinv * (z1h @ W1)) ; z2 = prelu(...) -> d_out (f32)
  gemm_mfma_bf16_kernel<<<gemmBlocks, 256, 0, stream>>>(z1h, wt1, dinv, zws, N);
  aggregate_kernel<<<(N + 3) / 4, 256, 0, stream>>>(zws, rs, col, dinv, b1, a1,
                                                    out, nullptr, N);

  // pooling -> g
  pool_kernel<<<(N + PROWS - 1) / PROWS, 256, 0, stream>>>(z1h, out, batch, N, g);
}